// Round 4
// baseline (10720.612 us; speedup 1.0000x reference)
//
#include <hip/hip_runtime.h>

#define F1 1024
#define F4 4096
#define NB 16      // batch
#define NT 512     // time steps
#define NWG 256    // recurrence workgroups

typedef float f32x4 __attribute__((ext_vector_type(4)));
typedef unsigned u32x4 __attribute__((ext_vector_type(4)));

// =====================================================================
// Kernel 1: Xi = A @ Wi + bias, with gate-column permutation so that the
// recurrence wg's 16 columns are contiguous:
//   original col n = g*1024 + wg*4 + j  ->  stored at wg*16 + g*4 + j
// =====================================================================
__global__ __launch_bounds__(256) void gemm_xi(
    const float* __restrict__ A, const float* __restrict__ Wi,
    const float* __restrict__ bias, float* __restrict__ Xi, int a_batch_major)
{
    __shared__ __align__(16) float As[16][68];
    __shared__ __align__(16) float Bs[16][68];
    const int tid = threadIdx.x;
    const int n0 = blockIdx.x * 64;
    const int m0 = blockIdx.y * 64;

    const int lrow = tid >> 2, lkq = tid & 3;   // A load: row, k-quarter
    const int bkr = tid >> 4, bnq = tid & 15;   // B load: k-row, n-quarter
    const int tm = tid & 15, tn = tid >> 4;     // compute: 4x4 micro tile

    const int m_l = m0 + lrow;
    const float* arow;
    if (a_batch_major) {
        int t = m_l >> 4, b = m_l & 15;
        arow = A + (size_t)(b * NT + t) * F1;
    } else {
        arow = A + (size_t)m_l * F1;
    }

    float acc[4][4];
#pragma unroll
    for (int i = 0; i < 4; i++)
#pragma unroll
        for (int j = 0; j < 4; j++) acc[i][j] = 0.f;

    for (int kc = 0; kc < F1; kc += 16) {
        float4 a4 = *(const float4*)(arow + kc + lkq * 4);
        float4 b4 = *(const float4*)(Wi + (size_t)(kc + bkr) * F4 + n0 + bnq * 4);
        __syncthreads();
        As[lkq * 4 + 0][lrow] = a4.x;
        As[lkq * 4 + 1][lrow] = a4.y;
        As[lkq * 4 + 2][lrow] = a4.z;
        As[lkq * 4 + 3][lrow] = a4.w;
        *(float4*)&Bs[bkr][bnq * 4] = b4;
        __syncthreads();
#pragma unroll
        for (int k = 0; k < 16; k++) {
            const float4 av = *(const float4*)&As[k][tm * 4];
            const float4 bv = *(const float4*)&Bs[k][tn * 4];
            float a_[4] = {av.x, av.y, av.z, av.w};
            float b_[4] = {bv.x, bv.y, bv.z, bv.w};
#pragma unroll
            for (int i = 0; i < 4; i++)
#pragma unroll
                for (int j = 0; j < 4; j++)
                    acc[i][j] = fmaf(a_[i], b_[j], acc[i][j]);
        }
    }

    const int n = n0 + tn * 4;
    const int g = n >> 10;
    const int wgi = (n & 1023) >> 2;
    const int np = wgi * 16 + g * 4;
    const float4 bi = *(const float4*)(bias + n);
#pragma unroll
    for (int i = 0; i < 4; i++) {
        int m = m0 + tm * 4 + i;
        float4 o;
        o.x = acc[i][0] + bi.x;
        o.y = acc[i][1] + bi.y;
        o.z = acc[i][2] + bi.z;
        o.w = acc[i][3] + bi.w;
        *(float4*)(Xi + (size_t)m * F4 + np) = o;
    }
}

// =====================================================================
// Kernel 2: persistent LSTM recurrence, one layer.
// Sync: distributed flag barrier. Arrival = per-wg flag store (distinct
// dwords, no RMW contention). Wait = wave 7 loads all 256 flags with ONE
// global_load_dwordx4 sc1 and spins until min >= target.
// h double-buffered by step parity via sc1 loads/stores (coherent point);
// no cache-maintenance instructions anywhere in the loop.
// =====================================================================
__global__ __launch_bounds__(512, 1) void lstm_recur(
    const float* __restrict__ Wh,   // [1024][4096] layer slice
    const float* __restrict__ Xi,   // [512*16][4096] permuted cols
    const float* __restrict__ c0,   // [16][1024] layer slice
    const float* __restrict__ h0,   // [16][1024] layer slice
    float* __restrict__ Hb,         // [2][16][1024] double-buffered broadcast (ws)
    unsigned* __restrict__ flags,   // [NWG] barrier flags (ws, memset 0)
    unsigned tbase,                 // barrier target base for this layer
    float* __restrict__ hseq,       // hseq[t*st_t + b*st_b + col]
    long long st_t, long long st_b,
    float* __restrict__ cfin, float* __restrict__ hfin)
{
    const int tid = threadIdx.x;
    const int wg = blockIdx.x;       // 0..255

    const int ks = tid >> 4;         // 0..31 (K slice)
    const int rb = (tid >> 2) & 3;   // 0..3  (row block)
    const int g = tid & 3;           // 0..3  (gate)

    __shared__ __align__(16) f32x4 hbuf4[16 * 257];  // h swizzled [16 rows][256+pad]
    __shared__ __align__(16) f32x4 red4[32 * 65];    // partials [32 ks][16r*4g + pad]
    __shared__ float gbuf[16 * 20];                  // gates [16 rows][16 + pad]

    // ---- Wh -> registers: wh[kk][j] = Wh[ks*32+kk][g*1024 + wg*4 + j]
    float wh[32][4];
    {
        const float* wp = Wh + (size_t)(ks * 32) * F4 + g * F1 + wg * 4;
#pragma unroll
        for (int kk = 0; kk < 32; kk++) {
            float4 w4 = *(const float4*)(wp + (size_t)kk * F4);
            wh[kk][0] = w4.x; wh[kk][1] = w4.y; wh[kk][2] = w4.z; wh[kk][3] = w4.w;
        }
    }

    // ---- c-state in registers of the 64 activation threads (= wave 0)
    const int ab = tid >> 2, aj = tid & 3;
    float creg = 0.f;
    if (tid < 64) creg = c0[ab * F1 + wg * 4 + aj];

    for (int t = 0; t < NT; ++t) {
        // ---- gather h (16x1024 fp32). t==0: cached read of h0.
        // t>0: sc1 loads (coherent point) of Hb[t&1].
        f32x4 vv[8];
        if (t == 0) {
#pragma unroll
            for (int c = 0; c < 8; ++c) {
                int f4 = c * 512 + tid;
                vv[c] = *((const f32x4*)h0 + f4);
            }
        } else {
            const f32x4* hsrc = (const f32x4*)(Hb + (size_t)(t & 1) * (NB * F1));
#pragma unroll
            for (int c = 0; c < 8; ++c) {
                int f4 = c * 512 + tid;
                asm volatile("global_load_dwordx4 %0, %1, off sc1"
                             : "=v"(vv[c]) : "v"(hsrc + f4));
            }
            asm volatile("s_waitcnt vmcnt(0)" ::: "memory");
        }
#pragma unroll
        for (int c = 0; c < 8; ++c) {
            int f4 = c * 512 + tid;
            int r = f4 >> 8, k4 = f4 & 255;
            hbuf4[r * 257 + (k4 ^ ((k4 >> 3) & 7))] = vv[c];
        }
        // ---- Xi prefetch (cached, L2-friendly)
        float xiv = 0.f;
        if (tid < 256) {
            int r = tid >> 4, c = tid & 15;
            xiv = Xi[(size_t)(t * NB + r) * F4 + wg * 16 + c];
        }
        __syncthreads();

        // ---- GEMM: acc[i][j] = sum_{k in slice} h[rb*4+i][k] * wh[k][j]
        float acc[4][4];
#pragma unroll
        for (int i = 0; i < 4; i++) {
            acc[i][0] = 0.f; acc[i][1] = 0.f; acc[i][2] = 0.f; acc[i][3] = 0.f;
        }
#pragma unroll
        for (int s = 0; s < 8; ++s) {
            const int k4 = (ks << 3) + s;
            const int slot = k4 ^ ((k4 >> 3) & 7);
            f32x4 hv[4];
#pragma unroll
            for (int i = 0; i < 4; i++) hv[i] = hbuf4[(rb * 4 + i) * 257 + slot];
#pragma unroll
            for (int i = 0; i < 4; i++) {
#pragma unroll
                for (int j = 0; j < 4; j++) {
                    acc[i][j] = fmaf(hv[i].x, wh[s * 4 + 0][j], acc[i][j]);
                    acc[i][j] = fmaf(hv[i].y, wh[s * 4 + 1][j], acc[i][j]);
                    acc[i][j] = fmaf(hv[i].z, wh[s * 4 + 2][j], acc[i][j]);
                    acc[i][j] = fmaf(hv[i].w, wh[s * 4 + 3][j], acc[i][j]);
                }
            }
        }
#pragma unroll
        for (int i = 0; i < 4; i++)
            red4[ks * 65 + (rb * 4 + i) * 4 + g] =
                (f32x4){acc[i][0], acc[i][1], acc[i][2], acc[i][3]};
        __syncthreads();

        // ---- reduce over 32 K-slices + Xi -> gates
        if (tid < 256) {
            const float* rf = (const float*)red4;
            float s = xiv;
#pragma unroll
            for (int kss = 0; kss < 32; ++kss) s += rf[kss * 260 + tid];
            int r = tid >> 4, c = tid & 15;
            gbuf[r * 20 + c] = s;
        }
        __syncthreads();

        // ---- activations (wave 0: 16 rows x 4 cols), h broadcast via sc1
        if (tid < 64) {
            float gi = gbuf[ab * 20 + 0 + aj];
            float gf = gbuf[ab * 20 + 4 + aj];
            float gg = gbuf[ab * 20 + 8 + aj];
            float go = gbuf[ab * 20 + 12 + aj];
            float si = 1.f / (1.f + __expf(-gi));
            float sf = 1.f / (1.f + __expf(-gf));
            float so = 1.f / (1.f + __expf(-go));
            float tg = 1.f - 2.f / (__expf(2.f * gg) + 1.f);
            float cn = sf * creg + si * tg;
            float tc = 1.f - 2.f / (__expf(2.f * cn) + 1.f);
            float hn = so * tc;
            creg = cn;
            int col = wg * 4 + aj;
            float* hp = Hb + (size_t)((t + 1) & 1) * (NB * F1) + ab * F1 + col;
            __hip_atomic_store(hp, hn, __ATOMIC_RELAXED, __HIP_MEMORY_SCOPE_AGENT);
            hseq[(size_t)t * st_t + (size_t)ab * st_b + col] = hn;
            if (t == NT - 1) {
                cfin[ab * F1 + col] = cn;
                hfin[ab * F1 + col] = hn;
            }
            // drain h stores to coherent point BEFORE arrival flag
            asm volatile("s_waitcnt vmcnt(0)" ::: "memory");
        }
        // ---- arrival: per-wg flag store (no contention)
        if (tid == 0) {
            __hip_atomic_store(flags + wg, tbase + (unsigned)(t + 1),
                               __ATOMIC_RELAXED, __HIP_MEMORY_SCOPE_AGENT);
        }
        // ---- wait: wave 7 loads all 256 flags with one dwordx4 sc1
        if (tid >= 448) {
            const unsigned target = tbase + (unsigned)(t + 1);
            const u32x4* fp = (const u32x4*)flags + (tid - 448);
            while (true) {
                u32x4 fv;
                asm volatile("global_load_dwordx4 %0, %1, off sc1"
                             : "=v"(fv) : "v"(fp));
                asm volatile("s_waitcnt vmcnt(0)" ::: "memory");
                int ok = (fv.x >= target) & (fv.y >= target) &
                         (fv.z >= target) & (fv.w >= target);
                if (__all(ok)) break;
            }
        }
        __syncthreads();
    }
}

// =====================================================================
// Launch
// =====================================================================
extern "C" void kernel_launch(void* const* d_in, const int* in_sizes, int n_in,
                              void* d_out, int out_size, void* d_ws, size_t ws_size,
                              hipStream_t stream) {
    const float* x = (const float*)d_in[0];     // [16][512][1024]
    const float* Wi = (const float*)d_in[1];    // [2][1024][4096]
    const float* Wh = (const float*)d_in[2];    // [2][1024][4096]
    const float* bias = (const float*)d_in[3];  // [2][4096]
    const float* c0 = (const float*)d_in[4];    // [2][16][1024]
    const float* h0 = (const float*)d_in[5];    // [2][16][1024]
    float* out = (float*)d_out;

    float* Xi = (float*)d_ws;                            // 8192*4096 fp32 = 128MB
    float* Hb = Xi + (size_t)8192 * 4096;                // [2][16][1024]
    unsigned* flags = (unsigned*)(Hb + 2 * NB * F1);     // [NWG] barrier flags

    float* hseq0 = out;                                  // park layer-0 h_seq in out region
    float* cfin = out + (size_t)NB * NT * F1;
    float* hfin = cfin + 2 * NB * F1;

    const size_t lw = (size_t)F1 * F4;
    dim3 ggrid(64, 128), gblk(256);

    hipMemsetAsync(flags, 0, NWG * sizeof(unsigned), stream);

    // ---------------- layer 0 ----------------
    gemm_xi<<<ggrid, gblk, 0, stream>>>(x, Wi, bias, Xi, 1);
    {
        const float* a0 = Wh;
        const float* a1 = Xi;
        const float* a2 = c0;
        const float* a3 = h0;
        float* a4 = Hb;
        unsigned* a5 = flags;
        unsigned a6 = 0;                   // tbase
        float* a7 = hseq0;                 // [t][b][f]
        long long a8 = (long long)NB * F1; // st_t
        long long a9 = F1;                 // st_b
        float* a10 = cfin;
        float* a11 = hfin;
        void* args[] = {&a0, &a1, &a2, &a3, &a4, &a5, &a6, &a7, &a8, &a9, &a10, &a11};
        hipLaunchCooperativeKernel((void*)lstm_recur, dim3(NWG), dim3(512), args, 0, stream);
    }
    // ---------------- layer 1 ----------------
    gemm_xi<<<ggrid, gblk, 0, stream>>>(hseq0, Wi + lw, bias + F4, Xi, 0);
    {
        const float* a0 = Wh + lw;
        const float* a1 = Xi;
        const float* a2 = c0 + NB * F1;
        const float* a3 = h0 + NB * F1;
        float* a4 = Hb;
        unsigned* a5 = flags;
        unsigned a6 = (unsigned)NT;        // tbase (flags continue past layer 0)
        float* a7 = out;                   // out[b][t][f]
        long long a8 = F1;                 // st_t
        long long a9 = (long long)NT * F1; // st_b
        float* a10 = cfin + NB * F1;
        float* a11 = hfin + NB * F1;
        void* args[] = {&a0, &a1, &a2, &a3, &a4, &a5, &a6, &a7, &a8, &a9, &a10, &a11};
        hipLaunchCooperativeKernel((void*)lstm_recur, dim3(NWG), dim3(512), args, 0, stream);
    }
}

// Round 5
// 10293.127 us; speedup vs baseline: 1.0415x; 1.0415x over previous
//
#include <hip/hip_runtime.h>

#define F1 1024
#define F4 4096
#define NB 16      // batch
#define NT 512     // time steps
#define NWG 256    // recurrence workgroups

typedef float f32x4 __attribute__((ext_vector_type(4)));
typedef unsigned u32x4 __attribute__((ext_vector_type(4)));

// =====================================================================
// Kernel 1: Xi = A @ Wi + bias, with gate-column permutation so that the
// recurrence wg's 16 columns are contiguous:
//   original col n = g*1024 + wg*4 + j  ->  stored at wg*16 + g*4 + j
// =====================================================================
__global__ __launch_bounds__(256) void gemm_xi(
    const float* __restrict__ A, const float* __restrict__ Wi,
    const float* __restrict__ bias, float* __restrict__ Xi, int a_batch_major)
{
    __shared__ __align__(16) float As[16][68];
    __shared__ __align__(16) float Bs[16][68];
    const int tid = threadIdx.x;
    const int n0 = blockIdx.x * 64;
    const int m0 = blockIdx.y * 64;

    const int lrow = tid >> 2, lkq = tid & 3;   // A load: row, k-quarter
    const int bkr = tid >> 4, bnq = tid & 15;   // B load: k-row, n-quarter
    const int tm = tid & 15, tn = tid >> 4;     // compute: 4x4 micro tile

    const int m_l = m0 + lrow;
    const float* arow;
    if (a_batch_major) {
        int t = m_l >> 4, b = m_l & 15;
        arow = A + (size_t)(b * NT + t) * F1;
    } else {
        arow = A + (size_t)m_l * F1;
    }

    float acc[4][4];
#pragma unroll
    for (int i = 0; i < 4; i++)
#pragma unroll
        for (int j = 0; j < 4; j++) acc[i][j] = 0.f;

    for (int kc = 0; kc < F1; kc += 16) {
        float4 a4 = *(const float4*)(arow + kc + lkq * 4);
        float4 b4 = *(const float4*)(Wi + (size_t)(kc + bkr) * F4 + n0 + bnq * 4);
        __syncthreads();
        As[lkq * 4 + 0][lrow] = a4.x;
        As[lkq * 4 + 1][lrow] = a4.y;
        As[lkq * 4 + 2][lrow] = a4.z;
        As[lkq * 4 + 3][lrow] = a4.w;
        *(float4*)&Bs[bkr][bnq * 4] = b4;
        __syncthreads();
#pragma unroll
        for (int k = 0; k < 16; k++) {
            const float4 av = *(const float4*)&As[k][tm * 4];
            const float4 bv = *(const float4*)&Bs[k][tn * 4];
            float a_[4] = {av.x, av.y, av.z, av.w};
            float b_[4] = {bv.x, bv.y, bv.z, bv.w};
#pragma unroll
            for (int i = 0; i < 4; i++)
#pragma unroll
                for (int j = 0; j < 4; j++)
                    acc[i][j] = fmaf(a_[i], b_[j], acc[i][j]);
        }
    }

    const int n = n0 + tn * 4;
    const int g = n >> 10;
    const int wgi = (n & 1023) >> 2;
    const int np = wgi * 16 + g * 4;
    const float4 bi = *(const float4*)(bias + n);
#pragma unroll
    for (int i = 0; i < 4; i++) {
        int m = m0 + tm * 4 + i;
        float4 o;
        o.x = acc[i][0] + bi.x;
        o.y = acc[i][1] + bi.y;
        o.z = acc[i][2] + bi.z;
        o.w = acc[i][3] + bi.w;
        *(float4*)(Xi + (size_t)m * F4 + np) = o;
    }
}

// =====================================================================
// Kernel 2: persistent LSTM recurrence, one layer.
// h exchange: h(t+1) is stored ONLY into hseq[t] (the layer output) with
// sc1/agent stores (write-through to IF). Readers use PLAIN CACHED loads
// of hseq[t-1] — a per-step FRESH address, so no XCD L2 can hold a stale
// line for it; first reader per XCD misses to IF, the rest hit local L2.
// This cuts the per-step broadcast from 16 MB of L2-bypassing sc1 reads
// to 512 KB of IF traffic + L2 hits.
// Sync: distributed flag barrier (per-wg flag slot, wave-7 dwordx4 sc1
// poll) — measured neutral vs atomic counter, kept for the sc1 poll.
// =====================================================================
__global__ __launch_bounds__(512, 1) void lstm_recur(
    const float* __restrict__ Wh,   // [1024][4096] layer slice
    const float* __restrict__ Xi,   // [512*16][4096] permuted cols
    const float* __restrict__ c0,   // [16][1024] layer slice
    const float* __restrict__ h0,   // [16][1024] layer slice
    unsigned* __restrict__ flags,   // [NWG] barrier flags (ws, memset 0)
    unsigned tbase,                 // barrier target base for this layer
    float* __restrict__ hseq,       // hseq[t*st_t + b*st_b + col] (h exchange + output)
    long long st_t, long long st_b,
    float* __restrict__ cfin, float* __restrict__ hfin)
{
    const int tid = threadIdx.x;
    const int wg = blockIdx.x;       // 0..255

    const int ks = tid >> 4;         // 0..31 (K slice)
    const int rb = (tid >> 2) & 3;   // 0..3  (row block)
    const int g = tid & 3;           // 0..3  (gate)

    __shared__ __align__(16) f32x4 hbuf4[16 * 257];  // h swizzled [16 rows][256+pad]
    __shared__ __align__(16) f32x4 red4[32 * 65];    // partials [32 ks][16r*4g + pad]
    __shared__ float gbuf[16 * 20];                  // gates [16 rows][16 + pad]

    // ---- Wh -> registers: wh[kk][j] = Wh[ks*32+kk][g*1024 + wg*4 + j]
    float wh[32][4];
    {
        const float* wp = Wh + (size_t)(ks * 32) * F4 + g * F1 + wg * 4;
#pragma unroll
        for (int kk = 0; kk < 32; kk++) {
            float4 w4 = *(const float4*)(wp + (size_t)kk * F4);
            wh[kk][0] = w4.x; wh[kk][1] = w4.y; wh[kk][2] = w4.z; wh[kk][3] = w4.w;
        }
    }

    // ---- c-state in registers of the 64 activation threads (= wave 0)
    const int ab = tid >> 2, aj = tid & 3;
    float creg = 0.f;
    if (tid < 64) creg = c0[ab * F1 + wg * 4 + aj];

    for (int t = 0; t < NT; ++t) {
        // ---- gather h(t): t==0 from h0; else cached reads of hseq[t-1]
        // (fresh address per step -> no stale L2 lines possible).
        const float* hs;
        long long rs;
        if (t == 0) { hs = h0; rs = F1; }
        else        { hs = hseq + (size_t)(t - 1) * st_t; rs = st_b; }
        f32x4 vv[8];
#pragma unroll
        for (int c = 0; c < 8; ++c) {
            int f4 = c * 512 + tid;
            int r = f4 >> 8, k4 = f4 & 255;
            vv[c] = *(const f32x4*)(hs + (size_t)r * rs + (size_t)k4 * 4);
        }
#pragma unroll
        for (int c = 0; c < 8; ++c) {
            int f4 = c * 512 + tid;
            int r = f4 >> 8, k4 = f4 & 255;
            hbuf4[r * 257 + (k4 ^ ((k4 >> 3) & 7))] = vv[c];
        }
        // ---- Xi prefetch (cached, L2-friendly)
        float xiv = 0.f;
        if (tid < 256) {
            int r = tid >> 4, c = tid & 15;
            xiv = Xi[(size_t)(t * NB + r) * F4 + wg * 16 + c];
        }
        __syncthreads();

        // ---- GEMM: acc[i][j] = sum_{k in slice} h[rb*4+i][k] * wh[k][j]
        float acc[4][4];
#pragma unroll
        for (int i = 0; i < 4; i++) {
            acc[i][0] = 0.f; acc[i][1] = 0.f; acc[i][2] = 0.f; acc[i][3] = 0.f;
        }
#pragma unroll
        for (int s = 0; s < 8; ++s) {
            const int k4 = (ks << 3) + s;
            const int slot = k4 ^ ((k4 >> 3) & 7);
            f32x4 hv[4];
#pragma unroll
            for (int i = 0; i < 4; i++) hv[i] = hbuf4[(rb * 4 + i) * 257 + slot];
#pragma unroll
            for (int i = 0; i < 4; i++) {
#pragma unroll
                for (int j = 0; j < 4; j++) {
                    acc[i][j] = fmaf(hv[i].x, wh[s * 4 + 0][j], acc[i][j]);
                    acc[i][j] = fmaf(hv[i].y, wh[s * 4 + 1][j], acc[i][j]);
                    acc[i][j] = fmaf(hv[i].z, wh[s * 4 + 2][j], acc[i][j]);
                    acc[i][j] = fmaf(hv[i].w, wh[s * 4 + 3][j], acc[i][j]);
                }
            }
        }
#pragma unroll
        for (int i = 0; i < 4; i++)
            red4[ks * 65 + (rb * 4 + i) * 4 + g] =
                (f32x4){acc[i][0], acc[i][1], acc[i][2], acc[i][3]};
        __syncthreads();

        // ---- reduce over 32 K-slices + Xi -> gates
        if (tid < 256) {
            const float* rf = (const float*)red4;
            float s = xiv;
#pragma unroll
            for (int kss = 0; kss < 32; ++kss) s += rf[kss * 260 + tid];
            int r = tid >> 4, c = tid & 15;
            gbuf[r * 20 + c] = s;
        }
        __syncthreads();

        // ---- activations (wave 0: 16 rows x 4 cols)
        if (tid < 64) {
            float gi = gbuf[ab * 20 + 0 + aj];
            float gf = gbuf[ab * 20 + 4 + aj];
            float gg = gbuf[ab * 20 + 8 + aj];
            float go = gbuf[ab * 20 + 12 + aj];
            float si = 1.f / (1.f + __expf(-gi));
            float sf = 1.f / (1.f + __expf(-gf));
            float so = 1.f / (1.f + __expf(-go));
            float tg = 1.f - 2.f / (__expf(2.f * gg) + 1.f);
            float cn = sf * creg + si * tg;
            float tc = 1.f - 2.f / (__expf(2.f * cn) + 1.f);
            float hn = so * tc;
            creg = cn;
            int col = wg * 4 + aj;
            // h(t+1) -> hseq[t]: sc1 write-through so the flag release
            // guarantees it is at the coherent point.
            float* hp = hseq + (size_t)t * st_t + (size_t)ab * st_b + col;
            __hip_atomic_store(hp, hn, __ATOMIC_RELAXED, __HIP_MEMORY_SCOPE_AGENT);
            if (t == NT - 1) {
                cfin[ab * F1 + col] = cn;
                hfin[ab * F1 + col] = hn;
            }
            // drain h stores to coherent point BEFORE arrival flag
            asm volatile("s_waitcnt vmcnt(0)" ::: "memory");
        }
        // ---- arrival: per-wg flag store (no contention)
        if (tid == 0) {
            __hip_atomic_store(flags + wg, tbase + (unsigned)(t + 1),
                               __ATOMIC_RELAXED, __HIP_MEMORY_SCOPE_AGENT);
        }
        // ---- wait: wave 7 loads all 256 flags with one dwordx4 sc1
        if (tid >= 448) {
            const unsigned target = tbase + (unsigned)(t + 1);
            const u32x4* fp = (const u32x4*)flags + (tid - 448);
            while (true) {
                u32x4 fv;
                asm volatile("global_load_dwordx4 %0, %1, off sc1"
                             : "=v"(fv) : "v"(fp));
                asm volatile("s_waitcnt vmcnt(0)" ::: "memory");
                int ok = (fv.x >= target) & (fv.y >= target) &
                         (fv.z >= target) & (fv.w >= target);
                if (__all(ok)) break;
            }
        }
        __syncthreads();
    }
}

// =====================================================================
// Launch
// =====================================================================
extern "C" void kernel_launch(void* const* d_in, const int* in_sizes, int n_in,
                              void* d_out, int out_size, void* d_ws, size_t ws_size,
                              hipStream_t stream) {
    const float* x = (const float*)d_in[0];     // [16][512][1024]
    const float* Wi = (const float*)d_in[1];    // [2][1024][4096]
    const float* Wh = (const float*)d_in[2];    // [2][1024][4096]
    const float* bias = (const float*)d_in[3];  // [2][4096]
    const float* c0 = (const float*)d_in[4];    // [2][16][1024]
    const float* h0 = (const float*)d_in[5];    // [2][16][1024]
    float* out = (float*)d_out;

    float* Xi = (float*)d_ws;                            // 8192*4096 fp32 = 128MB
    unsigned* flags = (unsigned*)(Xi + (size_t)8192 * 4096); // [NWG] barrier flags

    float* hseq0 = out;                                  // layer-0 h_seq in out region [t][b][f]
    float* cfin = out + (size_t)NB * NT * F1;
    float* hfin = cfin + 2 * NB * F1;

    const size_t lw = (size_t)F1 * F4;
    dim3 ggrid(64, 128), gblk(256);

    hipMemsetAsync(flags, 0, NWG * sizeof(unsigned), stream);

    // ---------------- layer 0 ----------------
    gemm_xi<<<ggrid, gblk, 0, stream>>>(x, Wi, bias, Xi, 1);
    {
        const float* a0 = Wh;
        const float* a1 = Xi;
        const float* a2 = c0;
        const float* a3 = h0;
        unsigned* a4 = flags;
        unsigned a5 = 0;                   // tbase
        float* a6 = hseq0;                 // [t][b][f]
        long long a7 = (long long)NB * F1; // st_t
        long long a8 = F1;                 // st_b
        float* a9 = cfin;
        float* a10 = hfin;
        void* args[] = {&a0, &a1, &a2, &a3, &a4, &a5, &a6, &a7, &a8, &a9, &a10};
        hipLaunchCooperativeKernel((void*)lstm_recur, dim3(NWG), dim3(512), args, 0, stream);
    }
    // ---------------- layer 1 ----------------
    gemm_xi<<<ggrid, gblk, 0, stream>>>(hseq0, Wi + lw, bias + F4, Xi, 0);
    {
        const float* a0 = Wh + lw;
        const float* a1 = Xi;
        const float* a2 = c0 + NB * F1;
        const float* a3 = h0 + NB * F1;
        unsigned* a4 = flags;
        unsigned a5 = (unsigned)NT;        // tbase (flags continue past layer 0)
        float* a6 = out;                   // out[b][t][f]
        long long a7 = F1;                 // st_t
        long long a8 = (long long)NT * F1; // st_b
        float* a9 = cfin + NB * F1;
        float* a10 = hfin + NB * F1;
        void* args[] = {&a0, &a1, &a2, &a3, &a4, &a5, &a6, &a7, &a8, &a9, &a10};
        hipLaunchCooperativeKernel((void*)lstm_recur, dim3(NWG), dim3(512), args, 0, stream);
    }
}

// Round 6
// 9172.369 us; speedup vs baseline: 1.1688x; 1.1222x over previous
//
#include <hip/hip_runtime.h>

#define F1 1024
#define F4 4096
#define NB 16      // batch
#define NT 512     // time steps
#define NWG 256    // recurrence workgroups

typedef float f32x4 __attribute__((ext_vector_type(4)));
typedef unsigned u32x4 __attribute__((ext_vector_type(4)));

// =====================================================================
// Kernel 1: Xi = A @ Wi + bias, with gate-column permutation so that the
// recurrence wg's 16 columns are contiguous:
//   original col n = g*1024 + wg*4 + j  ->  stored at wg*16 + g*4 + j
// =====================================================================
__global__ __launch_bounds__(256) void gemm_xi(
    const float* __restrict__ A, const float* __restrict__ Wi,
    const float* __restrict__ bias, float* __restrict__ Xi, int a_batch_major)
{
    __shared__ __align__(16) float As[16][68];
    __shared__ __align__(16) float Bs[16][68];
    const int tid = threadIdx.x;
    const int n0 = blockIdx.x * 64;
    const int m0 = blockIdx.y * 64;

    const int lrow = tid >> 2, lkq = tid & 3;   // A load: row, k-quarter
    const int bkr = tid >> 4, bnq = tid & 15;   // B load: k-row, n-quarter
    const int tm = tid & 15, tn = tid >> 4;     // compute: 4x4 micro tile

    const int m_l = m0 + lrow;
    const float* arow;
    if (a_batch_major) {
        int t = m_l >> 4, b = m_l & 15;
        arow = A + (size_t)(b * NT + t) * F1;
    } else {
        arow = A + (size_t)m_l * F1;
    }

    float acc[4][4];
#pragma unroll
    for (int i = 0; i < 4; i++)
#pragma unroll
        for (int j = 0; j < 4; j++) acc[i][j] = 0.f;

    for (int kc = 0; kc < F1; kc += 16) {
        float4 a4 = *(const float4*)(arow + kc + lkq * 4);
        float4 b4 = *(const float4*)(Wi + (size_t)(kc + bkr) * F4 + n0 + bnq * 4);
        __syncthreads();
        As[lkq * 4 + 0][lrow] = a4.x;
        As[lkq * 4 + 1][lrow] = a4.y;
        As[lkq * 4 + 2][lrow] = a4.z;
        As[lkq * 4 + 3][lrow] = a4.w;
        *(float4*)&Bs[bkr][bnq * 4] = b4;
        __syncthreads();
#pragma unroll
        for (int k = 0; k < 16; k++) {
            const float4 av = *(const float4*)&As[k][tm * 4];
            const float4 bv = *(const float4*)&Bs[k][tn * 4];
            float a_[4] = {av.x, av.y, av.z, av.w};
            float b_[4] = {bv.x, bv.y, bv.z, bv.w};
#pragma unroll
            for (int i = 0; i < 4; i++)
#pragma unroll
                for (int j = 0; j < 4; j++)
                    acc[i][j] = fmaf(a_[i], b_[j], acc[i][j]);
        }
    }

    const int n = n0 + tn * 4;
    const int g = n >> 10;
    const int wgi = (n & 1023) >> 2;
    const int np = wgi * 16 + g * 4;
    const float4 bi = *(const float4*)(bias + n);
#pragma unroll
    for (int i = 0; i < 4; i++) {
        int m = m0 + tm * 4 + i;
        float4 o;
        o.x = acc[i][0] + bi.x;
        o.y = acc[i][1] + bi.y;
        o.z = acc[i][2] + bi.z;
        o.w = acc[i][3] + bi.w;
        *(float4*)(Xi + (size_t)m * F4 + np) = o;
    }
}

// =====================================================================
// Kernel 2: persistent LSTM recurrence, one layer.
// h exchange (unchanged from R5): h(t+1) stored sc1 into hseq[t]; readers
// use plain cached loads of the per-step-fresh address (no stale lines).
// Sync (NEW): zero-contention barrier —
//   arrival:  per-wg flag store (256 distinct dwords, one-shot).
//   detect:   wg 0 wave 7 is the SOLE poller of the 256 flags.
//   release:  wg 0 wave 7 broadcasts epoch to 256 per-wg release words
//             (128 B apart = distinct lines); each member polls ONLY its
//             own word (1 poller per line, s_sleep-throttled).
// Rationale: R2/R4/R5 all had 256 wgs sc1-polling the same <=16 lines;
// coherent-point service (~25 ns/line-request) queues that to ~6 us per
// poll round — the invariant ~8.5-9 us/step across all three designs.
// =====================================================================
__global__ __launch_bounds__(512, 1) void lstm_recur(
    const float* __restrict__ Wh,   // [1024][4096] layer slice
    const float* __restrict__ Xi,   // [512*16][4096] permuted cols
    const float* __restrict__ c0,   // [16][1024] layer slice
    const float* __restrict__ h0,   // [16][1024] layer slice
    unsigned* __restrict__ flags,   // [NWG] arrival flags (ws, memset 0)
    unsigned* __restrict__ release, // [NWG*32] release words, 128B apart (ws, memset 0)
    unsigned tbase,                 // epoch base for this layer
    float* __restrict__ hseq,       // hseq[t*st_t + b*st_b + col] (h exchange + output)
    long long st_t, long long st_b,
    float* __restrict__ cfin, float* __restrict__ hfin)
{
    const int tid = threadIdx.x;
    const int wg = blockIdx.x;       // 0..255

    const int ks = tid >> 4;         // 0..31 (K slice)
    const int rb = (tid >> 2) & 3;   // 0..3  (row block)
    const int g = tid & 3;           // 0..3  (gate)

    __shared__ __align__(16) f32x4 hbuf4[16 * 257];  // h swizzled [16 rows][256+pad]
    __shared__ __align__(16) f32x4 red4[32 * 65];    // partials [32 ks][16r*4g + pad]
    __shared__ float gbuf[16 * 20];                  // gates [16 rows][16 + pad]

    // ---- Wh -> registers: wh[kk][j] = Wh[ks*32+kk][g*1024 + wg*4 + j]
    float wh[32][4];
    {
        const float* wp = Wh + (size_t)(ks * 32) * F4 + g * F1 + wg * 4;
#pragma unroll
        for (int kk = 0; kk < 32; kk++) {
            float4 w4 = *(const float4*)(wp + (size_t)kk * F4);
            wh[kk][0] = w4.x; wh[kk][1] = w4.y; wh[kk][2] = w4.z; wh[kk][3] = w4.w;
        }
    }

    // ---- c-state in registers of the 64 activation threads (= wave 0)
    const int ab = tid >> 2, aj = tid & 3;
    float creg = 0.f;
    if (tid < 64) creg = c0[ab * F1 + wg * 4 + aj];

    for (int t = 0; t < NT; ++t) {
        // ---- gather h(t): t==0 from h0; else cached reads of hseq[t-1]
        // (fresh address per step -> no stale L2 lines possible).
        const float* hs;
        long long rs;
        if (t == 0) { hs = h0; rs = F1; }
        else        { hs = hseq + (size_t)(t - 1) * st_t; rs = st_b; }
        f32x4 vv[8];
#pragma unroll
        for (int c = 0; c < 8; ++c) {
            int f4 = c * 512 + tid;
            int r = f4 >> 8, k4 = f4 & 255;
            vv[c] = *(const f32x4*)(hs + (size_t)r * rs + (size_t)k4 * 4);
        }
#pragma unroll
        for (int c = 0; c < 8; ++c) {
            int f4 = c * 512 + tid;
            int r = f4 >> 8, k4 = f4 & 255;
            hbuf4[r * 257 + (k4 ^ ((k4 >> 3) & 7))] = vv[c];
        }
        // ---- Xi prefetch (cached, L2-friendly)
        float xiv = 0.f;
        if (tid < 256) {
            int r = tid >> 4, c = tid & 15;
            xiv = Xi[(size_t)(t * NB + r) * F4 + wg * 16 + c];
        }
        __syncthreads();

        // ---- GEMM: acc[i][j] = sum_{k in slice} h[rb*4+i][k] * wh[k][j]
        float acc[4][4];
#pragma unroll
        for (int i = 0; i < 4; i++) {
            acc[i][0] = 0.f; acc[i][1] = 0.f; acc[i][2] = 0.f; acc[i][3] = 0.f;
        }
#pragma unroll
        for (int s = 0; s < 8; ++s) {
            const int k4 = (ks << 3) + s;
            const int slot = k4 ^ ((k4 >> 3) & 7);
            f32x4 hv[4];
#pragma unroll
            for (int i = 0; i < 4; i++) hv[i] = hbuf4[(rb * 4 + i) * 257 + slot];
#pragma unroll
            for (int i = 0; i < 4; i++) {
#pragma unroll
                for (int j = 0; j < 4; j++) {
                    acc[i][j] = fmaf(hv[i].x, wh[s * 4 + 0][j], acc[i][j]);
                    acc[i][j] = fmaf(hv[i].y, wh[s * 4 + 1][j], acc[i][j]);
                    acc[i][j] = fmaf(hv[i].z, wh[s * 4 + 2][j], acc[i][j]);
                    acc[i][j] = fmaf(hv[i].w, wh[s * 4 + 3][j], acc[i][j]);
                }
            }
        }
#pragma unroll
        for (int i = 0; i < 4; i++)
            red4[ks * 65 + (rb * 4 + i) * 4 + g] =
                (f32x4){acc[i][0], acc[i][1], acc[i][2], acc[i][3]};
        __syncthreads();

        // ---- reduce over 32 K-slices + Xi -> gates
        if (tid < 256) {
            const float* rf = (const float*)red4;
            float s = xiv;
#pragma unroll
            for (int kss = 0; kss < 32; ++kss) s += rf[kss * 260 + tid];
            int r = tid >> 4, c = tid & 15;
            gbuf[r * 20 + c] = s;
        }
        __syncthreads();

        // ---- activations (wave 0: 16 rows x 4 cols)
        if (tid < 64) {
            float gi = gbuf[ab * 20 + 0 + aj];
            float gf = gbuf[ab * 20 + 4 + aj];
            float gg = gbuf[ab * 20 + 8 + aj];
            float go = gbuf[ab * 20 + 12 + aj];
            float si = 1.f / (1.f + __expf(-gi));
            float sf = 1.f / (1.f + __expf(-gf));
            float so = 1.f / (1.f + __expf(-go));
            float tg = 1.f - 2.f / (__expf(2.f * gg) + 1.f);
            float cn = sf * creg + si * tg;
            float tc = 1.f - 2.f / (__expf(2.f * cn) + 1.f);
            float hn = so * tc;
            creg = cn;
            int col = wg * 4 + aj;
            // h(t+1) -> hseq[t]: sc1 write-through to the coherent point.
            float* hp = hseq + (size_t)t * st_t + (size_t)ab * st_b + col;
            __hip_atomic_store(hp, hn, __ATOMIC_RELAXED, __HIP_MEMORY_SCOPE_AGENT);
            if (t == NT - 1) {
                cfin[ab * F1 + col] = cn;
                hfin[ab * F1 + col] = hn;
            }
            // drain h stores to coherent point BEFORE arrival flag
            asm volatile("s_waitcnt vmcnt(0)" ::: "memory");
        }
        // ---- arrival: per-wg flag store (distinct dwords, one-shot)
        if (tid == 0) {
            __hip_atomic_store(flags + wg, tbase + (unsigned)(t + 1),
                               __ATOMIC_RELAXED, __HIP_MEMORY_SCOPE_AGENT);
        }
        const unsigned target = tbase + (unsigned)(t + 1);
        if (wg == 0) {
            // ---- detect: wg 0 wave 7 = sole poller of the 256 flags
            if (tid >= 448) {
                const int lane = tid - 448;
                const u32x4* fp = (const u32x4*)flags + lane;
                while (true) {
                    u32x4 fv;
                    asm volatile("global_load_dwordx4 %0, %1, off sc1"
                                 : "=v"(fv) : "v"(fp));
                    asm volatile("s_waitcnt vmcnt(0)" ::: "memory");
                    int ok = (fv.x >= target) & (fv.y >= target) &
                             (fv.z >= target) & (fv.w >= target);
                    if (__all(ok)) break;
                }
                // ---- release: broadcast epoch to 256 per-wg words
                // (128 B apart; 64 lanes x 4 stores, all in flight)
#pragma unroll
                for (int it = 0; it < 4; ++it) {
                    unsigned* rp = release + (size_t)(it * 64 + lane) * 32;
                    __hip_atomic_store(rp, target, __ATOMIC_RELAXED,
                                       __HIP_MEMORY_SCOPE_AGENT);
                }
            }
        } else {
            // ---- wait: one lane polls ONLY this wg's release word
            if (tid == 448) {
                const unsigned* rp = release + (size_t)wg * 32;
                while (true) {
                    unsigned v;
                    asm volatile("global_load_dword %0, %1, off sc1"
                                 : "=v"(v) : "v"(rp));
                    asm volatile("s_waitcnt vmcnt(0)" ::: "memory");
                    if (v >= target) break;
                    asm volatile("s_sleep 1");
                }
            }
        }
        __syncthreads();
    }
}

// =====================================================================
// Launch
// =====================================================================
extern "C" void kernel_launch(void* const* d_in, const int* in_sizes, int n_in,
                              void* d_out, int out_size, void* d_ws, size_t ws_size,
                              hipStream_t stream) {
    const float* x = (const float*)d_in[0];     // [16][512][1024]
    const float* Wi = (const float*)d_in[1];    // [2][1024][4096]
    const float* Wh = (const float*)d_in[2];    // [2][1024][4096]
    const float* bias = (const float*)d_in[3];  // [2][4096]
    const float* c0 = (const float*)d_in[4];    // [2][16][1024]
    const float* h0 = (const float*)d_in[5];    // [2][16][1024]
    float* out = (float*)d_out;

    float* Xi = (float*)d_ws;                                // 8192*4096 fp32 = 128MB
    unsigned* flags = (unsigned*)(Xi + (size_t)8192 * 4096); // [NWG]
    unsigned* release = flags + NWG;                         // [NWG*32] (128B-spaced words)

    float* hseq0 = out;                                  // layer-0 h_seq in out region [t][b][f]
    float* cfin = out + (size_t)NB * NT * F1;
    float* hfin = cfin + 2 * NB * F1;

    const size_t lw = (size_t)F1 * F4;
    dim3 ggrid(64, 128), gblk(256);

    hipMemsetAsync(flags, 0, (NWG + NWG * 32) * sizeof(unsigned), stream);

    // ---------------- layer 0 ----------------
    gemm_xi<<<ggrid, gblk, 0, stream>>>(x, Wi, bias, Xi, 1);
    {
        const float* a0 = Wh;
        const float* a1 = Xi;
        const float* a2 = c0;
        const float* a3 = h0;
        unsigned* a4 = flags;
        unsigned* a5 = release;
        unsigned a6 = 0;                   // tbase
        float* a7 = hseq0;                 // [t][b][f]
        long long a8 = (long long)NB * F1; // st_t
        long long a9 = F1;                 // st_b
        float* a10 = cfin;
        float* a11 = hfin;
        void* args[] = {&a0, &a1, &a2, &a3, &a4, &a5, &a6, &a7, &a8, &a9, &a10, &a11};
        hipLaunchCooperativeKernel((void*)lstm_recur, dim3(NWG), dim3(512), args, 0, stream);
    }
    // ---------------- layer 1 ----------------
    gemm_xi<<<ggrid, gblk, 0, stream>>>(hseq0, Wi + lw, bias + F4, Xi, 0);
    {
        const float* a0 = Wh + lw;
        const float* a1 = Xi;
        const float* a2 = c0 + NB * F1;
        const float* a3 = h0 + NB * F1;
        unsigned* a4 = flags;
        unsigned* a5 = release;
        unsigned a6 = (unsigned)NT;        // tbase (epochs continue past layer 0)
        float* a7 = out;                   // out[b][t][f]
        long long a8 = F1;                 // st_t
        long long a9 = (long long)NT * F1; // st_b
        float* a10 = cfin + NB * F1;
        float* a11 = hfin + NB * F1;
        void* args[] = {&a0, &a1, &a2, &a3, &a4, &a5, &a6, &a7, &a8, &a9, &a10, &a11};
        hipLaunchCooperativeKernel((void*)lstm_recur, dim3(NWG), dim3(512), args, 0, stream);
    }
}

// Round 7
// 8877.521 us; speedup vs baseline: 1.2076x; 1.0332x over previous
//
#include <hip/hip_runtime.h>

#define F1 1024
#define F4 4096
#define NB 16      // batch
#define NT 512     // time steps
#define NWG 256    // recurrence workgroups
#define EPM (NT * NWG)  // epoch mirror stride (u32s)

typedef float f32x4 __attribute__((ext_vector_type(4)));
typedef unsigned u32x4 __attribute__((ext_vector_type(4)));

// =====================================================================
// Kernel 1: Xi = A @ Wi + bias, with gate-column permutation so that the
// recurrence wg's 16 columns are contiguous:
//   original col n = g*1024 + wg*4 + j  ->  stored at wg*16 + g*4 + j
// =====================================================================
__global__ __launch_bounds__(256) void gemm_xi(
    const float* __restrict__ A, const float* __restrict__ Wi,
    const float* __restrict__ bias, float* __restrict__ Xi, int a_batch_major)
{
    __shared__ __align__(16) float As[16][68];
    __shared__ __align__(16) float Bs[16][68];
    const int tid = threadIdx.x;
    const int n0 = blockIdx.x * 64;
    const int m0 = blockIdx.y * 64;

    const int lrow = tid >> 2, lkq = tid & 3;   // A load: row, k-quarter
    const int bkr = tid >> 4, bnq = tid & 15;   // B load: k-row, n-quarter
    const int tm = tid & 15, tn = tid >> 4;     // compute: 4x4 micro tile

    const int m_l = m0 + lrow;
    const float* arow;
    if (a_batch_major) {
        int t = m_l >> 4, b = m_l & 15;
        arow = A + (size_t)(b * NT + t) * F1;
    } else {
        arow = A + (size_t)m_l * F1;
    }

    float acc[4][4];
#pragma unroll
    for (int i = 0; i < 4; i++)
#pragma unroll
        for (int j = 0; j < 4; j++) acc[i][j] = 0.f;

    for (int kc = 0; kc < F1; kc += 16) {
        float4 a4 = *(const float4*)(arow + kc + lkq * 4);
        float4 b4 = *(const float4*)(Wi + (size_t)(kc + bkr) * F4 + n0 + bnq * 4);
        __syncthreads();
        As[lkq * 4 + 0][lrow] = a4.x;
        As[lkq * 4 + 1][lrow] = a4.y;
        As[lkq * 4 + 2][lrow] = a4.z;
        As[lkq * 4 + 3][lrow] = a4.w;
        *(float4*)&Bs[bkr][bnq * 4] = b4;
        __syncthreads();
#pragma unroll
        for (int k = 0; k < 16; k++) {
            const float4 av = *(const float4*)&As[k][tm * 4];
            const float4 bv = *(const float4*)&Bs[k][tn * 4];
            float a_[4] = {av.x, av.y, av.z, av.w};
            float b_[4] = {bv.x, bv.y, bv.z, bv.w};
#pragma unroll
            for (int i = 0; i < 4; i++)
#pragma unroll
                for (int j = 0; j < 4; j++)
                    acc[i][j] = fmaf(a_[i], b_[j], acc[i][j]);
        }
    }

    const int n = n0 + tn * 4;
    const int g = n >> 10;
    const int wgi = (n & 1023) >> 2;
    const int np = wgi * 16 + g * 4;
    const float4 bi = *(const float4*)(bias + n);
#pragma unroll
    for (int i = 0; i < 4; i++) {
        int m = m0 + tm * 4 + i;
        float4 o;
        o.x = acc[i][0] + bi.x;
        o.y = acc[i][1] + bi.y;
        o.z = acc[i][2] + bi.z;
        o.w = acc[i][3] + bi.w;
        *(float4*)(Xi + (size_t)m * F4 + np) = o;
    }
}

// =====================================================================
// Kernel 2: persistent LSTM recurrence, one layer — DATAFLOW, no global
// barrier. Producers (wave 0) store h(t+1) sc1 into hseq[t] (fresh addr),
// drain vmcnt, then publish a per-producer epoch to 8 XCD-spread mirrors.
// Consumers: wave 7 polls ONE mirror (wg&7 -> ~32 pollers/line) for all
// 256 producer epochs of the previous step, then __syncthreads releases
// the wg to do the cached gather. No slot reuse within a layer -> no WAR
// hazard -> no reverse barrier. Removes the centralized detect->release->
// observe IF hops of R6.
// =====================================================================
__global__ __launch_bounds__(512, 1) void lstm_recur(
    const float* __restrict__ Wh,   // [1024][4096] layer slice
    const float* __restrict__ Xi,   // [512*16][4096] permuted cols
    const float* __restrict__ c0,   // [16][1024] layer slice
    const float* __restrict__ h0,   // [16][1024] layer slice
    unsigned* __restrict__ ep,      // [8][NT][NWG] epoch mirrors (ws, memset 0)
    unsigned tbase,                 // epoch base for this layer
    float* __restrict__ hseq,       // hseq[t*st_t + b*st_b + col] (h exchange + output)
    long long st_t, long long st_b,
    float* __restrict__ cfin, float* __restrict__ hfin)
{
    const int tid = threadIdx.x;
    const int wg = blockIdx.x;       // 0..255

    const int ks = tid >> 4;         // 0..31 (K slice)
    const int rb = (tid >> 2) & 3;   // 0..3  (row block)
    const int g = tid & 3;           // 0..3  (gate)

    __shared__ __align__(16) f32x4 hbuf4[16 * 257];  // h swizzled [16 rows][256+pad]
    __shared__ __align__(16) f32x4 red4[32 * 65];    // partials [32 ks][16r*4g + pad]
    __shared__ float gbuf[16 * 20];                  // gates [16 rows][16 + pad]

    // ---- Wh -> registers: wh[kk][j] = Wh[ks*32+kk][g*1024 + wg*4 + j]
    float wh[32][4];
    {
        const float* wp = Wh + (size_t)(ks * 32) * F4 + g * F1 + wg * 4;
#pragma unroll
        for (int kk = 0; kk < 32; kk++) {
            float4 w4 = *(const float4*)(wp + (size_t)kk * F4);
            wh[kk][0] = w4.x; wh[kk][1] = w4.y; wh[kk][2] = w4.z; wh[kk][3] = w4.w;
        }
    }

    // ---- c-state in registers of the 64 activation threads (= wave 0)
    const int ab = tid >> 2, aj = tid & 3;
    float creg = 0.f;
    if (tid < 64) creg = c0[ab * F1 + wg * 4 + aj];

    for (int t = 0; t < NT; ++t) {
        // ---- detect: h(t) ready? wave 7 polls this wg's mirror (sole-ish
        // pollers: ~32 wgs share a mirror). Skipped at t==0 (h0 is input).
        if (t > 0 && tid >= 448) {
            const int lane = tid - 448;
            const unsigned target = tbase + (unsigned)t;
            const u32x4* fp = (const u32x4*)(ep + (size_t)(wg & 7) * EPM
                                                + (size_t)(t - 1) * NWG) + lane;
            while (true) {
                u32x4 fv;
                asm volatile("global_load_dwordx4 %0, %1, off sc1"
                             : "=v"(fv) : "v"(fp));
                asm volatile("s_waitcnt vmcnt(0)" ::: "memory");
                int ok = (fv.x >= target) & (fv.y >= target) &
                         (fv.z >= target) & (fv.w >= target);
                if (__all(ok)) break;
            }
        }
        __syncthreads();   // S1: release gather

        // ---- gather h(t): t==0 from h0; else cached reads of hseq[t-1]
        // (fresh address per step -> no stale L2 lines possible).
        const float* hs;
        long long rs;
        if (t == 0) { hs = h0; rs = F1; }
        else        { hs = hseq + (size_t)(t - 1) * st_t; rs = st_b; }
        f32x4 vv[8];
#pragma unroll
        for (int c = 0; c < 8; ++c) {
            int f4 = c * 512 + tid;
            int r = f4 >> 8, k4 = f4 & 255;
            vv[c] = *(const f32x4*)(hs + (size_t)r * rs + (size_t)k4 * 4);
        }
#pragma unroll
        for (int c = 0; c < 8; ++c) {
            int f4 = c * 512 + tid;
            int r = f4 >> 8, k4 = f4 & 255;
            hbuf4[r * 257 + (k4 ^ ((k4 >> 3) & 7))] = vv[c];
        }
        // ---- Xi prefetch (cached, L2-friendly)
        float xiv = 0.f;
        if (tid < 256) {
            int r = tid >> 4, c = tid & 15;
            xiv = Xi[(size_t)(t * NB + r) * F4 + wg * 16 + c];
        }
        __syncthreads();   // S2: hbuf ready

        // ---- GEMM: acc[i][j] = sum_{k in slice} h[rb*4+i][k] * wh[k][j]
        float acc[4][4];
#pragma unroll
        for (int i = 0; i < 4; i++) {
            acc[i][0] = 0.f; acc[i][1] = 0.f; acc[i][2] = 0.f; acc[i][3] = 0.f;
        }
#pragma unroll
        for (int s = 0; s < 8; ++s) {
            const int k4 = (ks << 3) + s;
            const int slot = k4 ^ ((k4 >> 3) & 7);
            f32x4 hv[4];
#pragma unroll
            for (int i = 0; i < 4; i++) hv[i] = hbuf4[(rb * 4 + i) * 257 + slot];
#pragma unroll
            for (int i = 0; i < 4; i++) {
#pragma unroll
                for (int j = 0; j < 4; j++) {
                    acc[i][j] = fmaf(hv[i].x, wh[s * 4 + 0][j], acc[i][j]);
                    acc[i][j] = fmaf(hv[i].y, wh[s * 4 + 1][j], acc[i][j]);
                    acc[i][j] = fmaf(hv[i].z, wh[s * 4 + 2][j], acc[i][j]);
                    acc[i][j] = fmaf(hv[i].w, wh[s * 4 + 3][j], acc[i][j]);
                }
            }
        }
#pragma unroll
        for (int i = 0; i < 4; i++)
            red4[ks * 65 + (rb * 4 + i) * 4 + g] =
                (f32x4){acc[i][0], acc[i][1], acc[i][2], acc[i][3]};
        __syncthreads();   // S3: red4 ready

        // ---- reduce over 32 K-slices + Xi -> gates
        if (tid < 256) {
            const float* rf = (const float*)red4;
            float s = xiv;
#pragma unroll
            for (int kss = 0; kss < 32; ++kss) s += rf[kss * 260 + tid];
            int r = tid >> 4, c = tid & 15;
            gbuf[r * 20 + c] = s;
        }
        __syncthreads();   // S4: gbuf ready

        // ---- activations (wave 0: 16 rows x 4 cols) + epoch publish
        if (tid < 64) {
            float gi = gbuf[ab * 20 + 0 + aj];
            float gf = gbuf[ab * 20 + 4 + aj];
            float gg = gbuf[ab * 20 + 8 + aj];
            float go = gbuf[ab * 20 + 12 + aj];
            float si = 1.f / (1.f + __expf(-gi));
            float sf = 1.f / (1.f + __expf(-gf));
            float so = 1.f / (1.f + __expf(-go));
            float tg = 1.f - 2.f / (__expf(2.f * gg) + 1.f);
            float cn = sf * creg + si * tg;
            float tc = 1.f - 2.f / (__expf(2.f * cn) + 1.f);
            float hn = so * tc;
            creg = cn;
            int col = wg * 4 + aj;
            // h(t+1) -> hseq[t]: sc1 write-through to the coherent point.
            float* hp = hseq + (size_t)t * st_t + (size_t)ab * st_b + col;
            __hip_atomic_store(hp, hn, __ATOMIC_RELAXED, __HIP_MEMORY_SCOPE_AGENT);
            if (t == NT - 1) {
                cfin[ab * F1 + col] = cn;
                hfin[ab * F1 + col] = hn;
            }
            // drain data stores to coherent point, THEN publish epoch to
            // 8 mirrors (lanes 0-7, one store each).
            asm volatile("s_waitcnt vmcnt(0)" ::: "memory");
            if (tid < 8) {
                __hip_atomic_store(ep + (size_t)tid * EPM + (size_t)t * NWG + wg,
                                   tbase + (unsigned)(t + 1),
                                   __ATOMIC_RELAXED, __HIP_MEMORY_SCOPE_AGENT);
            }
        }
        // no trailing barrier — next iteration's poll + S1 is the sync
    }
}

// =====================================================================
// Launch
// =====================================================================
extern "C" void kernel_launch(void* const* d_in, const int* in_sizes, int n_in,
                              void* d_out, int out_size, void* d_ws, size_t ws_size,
                              hipStream_t stream) {
    const float* x = (const float*)d_in[0];     // [16][512][1024]
    const float* Wi = (const float*)d_in[1];    // [2][1024][4096]
    const float* Wh = (const float*)d_in[2];    // [2][1024][4096]
    const float* bias = (const float*)d_in[3];  // [2][4096]
    const float* c0 = (const float*)d_in[4];    // [2][16][1024]
    const float* h0 = (const float*)d_in[5];    // [2][16][1024]
    float* out = (float*)d_out;

    float* Xi = (float*)d_ws;                            // 8192*4096 fp32 = 128MB
    unsigned* ep = (unsigned*)(Xi + (size_t)8192 * 4096); // [8][NT][NWG] = 4MB

    float* hseq0 = out;                                  // layer-0 h_seq in out region [t][b][f]
    float* cfin = out + (size_t)NB * NT * F1;
    float* hfin = cfin + 2 * NB * F1;

    const size_t lw = (size_t)F1 * F4;
    dim3 ggrid(64, 128), gblk(256);

    // epochs must start 0 (ws is poisoned 0xAA -> would false-trigger polls)
    hipMemsetAsync(ep, 0, (size_t)8 * EPM * sizeof(unsigned), stream);

    // ---------------- layer 0 ----------------
    gemm_xi<<<ggrid, gblk, 0, stream>>>(x, Wi, bias, Xi, 1);
    {
        const float* a0 = Wh;
        const float* a1 = Xi;
        const float* a2 = c0;
        const float* a3 = h0;
        unsigned* a4 = ep;
        unsigned a5 = 0;                   // tbase
        float* a6 = hseq0;                 // [t][b][f]
        long long a7 = (long long)NB * F1; // st_t
        long long a8 = F1;                 // st_b
        float* a9 = cfin;
        float* a10 = hfin;
        void* args[] = {&a0, &a1, &a2, &a3, &a4, &a5, &a6, &a7, &a8, &a9, &a10};
        hipLaunchCooperativeKernel((void*)lstm_recur, dim3(NWG), dim3(512), args, 0, stream);
    }
    // ---------------- layer 1 ----------------
    gemm_xi<<<ggrid, gblk, 0, stream>>>(hseq0, Wi + lw, bias + F4, Xi, 0);
    {
        const float* a0 = Wh + lw;
        const float* a1 = Xi;
        const float* a2 = c0 + NB * F1;
        const float* a3 = h0 + NB * F1;
        unsigned* a4 = ep;
        unsigned a5 = (unsigned)NT;        // tbase (epochs continue past layer 0)
        float* a6 = out;                   // out[b][t][f]
        long long a7 = F1;                 // st_t
        long long a8 = (long long)NT * F1; // st_b
        float* a9 = cfin + NB * F1;
        float* a10 = hfin + NB * F1;
        void* args[] = {&a0, &a1, &a2, &a3, &a4, &a5, &a6, &a7, &a8, &a9, &a10};
        hipLaunchCooperativeKernel((void*)lstm_recur, dim3(NWG), dim3(512), args, 0, stream);
    }
}